// Round 1
// baseline (310.409 us; speedup 1.0000x reference)
//
#include <hip/hip_runtime.h>
#include <math.h>

#define H 1024
#define S 32768
#define NBLK (S / 16)  // 2048 energy blocks, 16 rows each

// ws layout (floats):
// [0,1024)      v = W^T @ hidden
// [1024]        counter (uint, zeroed together with v)
// [1088,3136)   per-block max partials   (float4-aligned)
// [3136,5184)   per-block sumexp partials
// energies live in d_out (finalized in-place by the last K2 block)

// K1: v[h] = sum_d W[d*H+h] * hidden[d].
// grid (4, 64): x = column group of 256, y = d-group of 16 rows.
__global__ __launch_bounds__(256) void compute_v(const float* __restrict__ W,
                                                 const float* __restrict__ hidden,
                                                 float* __restrict__ v) {
    int h = blockIdx.x * 256 + threadIdx.x;
    int d0 = blockIdx.y * 16;
    float acc = 0.f;
#pragma unroll
    for (int j = 0; j < 16; ++j) {
        int d = d0 + j;
        acc += W[(size_t)d * H + h] * hidden[d];  // coalesced across lanes
    }
    atomicAdd(&v[h], acc);
}

// online-softmax merge of (M,Sv) with (Mo,So); args must be simple lvalues
#define MERGE(M, Sv, Mo, So)                                   \
    do {                                                       \
        float _mn = fmaxf((M), (Mo));                          \
        (Sv) = (Sv) * __expf((M) - _mn) + (So) * __expf((Mo) - _mn); \
        (M) = _mn;                                             \
    } while (0)

// K2 (fused): energies[s] = enc[s,:] . v ; per-block (max,sumexp) partials;
// the LAST block to finish (threadfence-reduction pattern) combines the
// 2048 partials and finalizes the softmax in-place on d_out.
// 4 waves/block, 4 rows/wave -> 16 rows/block, grid = S/16 = 2048.
__global__ __launch_bounds__(256) void energies_fused(const float* __restrict__ enc,
                                                      const float* __restrict__ v,
                                                      float* __restrict__ out,
                                                      float* __restrict__ pmax,
                                                      float* __restrict__ psum,
                                                      unsigned* __restrict__ counter) {
    const int lane = threadIdx.x & 63;
    const int wave = threadIdx.x >> 6;
    const int tid = threadIdx.x;

    const float4* v4 = (const float4*)v;
    float4 va = v4[lane];
    float4 vb = v4[64 + lane];
    float4 vc = v4[128 + lane];
    float4 vd = v4[192 + lane];

    const int s0 = blockIdx.x * 16 + wave * 4;
    const float4* base = (const float4*)(enc + (size_t)s0 * H);

    float dot[4];
#pragma unroll
    for (int r = 0; r < 4; ++r) {
        const float4* row = base + r * (H / 4);
        float4 a = row[lane];
        float4 b = row[64 + lane];
        float4 c = row[128 + lane];
        float4 d = row[192 + lane];
        float t = a.x * va.x + a.y * va.y + a.z * va.z + a.w * va.w;
        t += b.x * vb.x + b.y * vb.y + b.z * vb.z + b.w * vb.w;
        t += c.x * vc.x + c.y * vc.y + c.z * vc.z + c.w * vc.w;
        t += d.x * vd.x + d.y * vd.y + d.z * vd.z + d.w * vd.w;
        dot[r] = t;
    }

    // 4 interleaved butterfly reductions (all lanes end with full sums)
#pragma unroll
    for (int off = 32; off > 0; off >>= 1) {
#pragma unroll
        for (int r = 0; r < 4; ++r) dot[r] += __shfl_xor(dot[r], off, 64);
    }

    if (lane == 0) {
        float4 e = make_float4(dot[0], dot[1], dot[2], dot[3]);
        *(float4*)(out + s0) = e;
    }

    float m = fmaxf(fmaxf(dot[0], dot[1]), fmaxf(dot[2], dot[3]));
    float sum = __expf(dot[0] - m) + __expf(dot[1] - m) +
                __expf(dot[2] - m) + __expf(dot[3] - m);

    __shared__ float wm[4], wsum[4];
    __shared__ int sLast;
    if (lane == 0) { wm[wave] = m; wsum[wave] = sum; }
    // barrier drains each thread's vmcnt -> all this block's energy stores
    // have left the CU before thread 0 publishes the partial.
    __syncthreads();
    if (tid == 0) {
        float M = wm[0], Sm = wsum[0];
#pragma unroll
        for (int w = 1; w < 4; ++w) MERGE(M, Sm, wm[w], wsum[w]);
        pmax[blockIdx.x] = M;
        psum[blockIdx.x] = Sm;
        __threadfence();  // release: wb this XCD's L2 (partials + energies)
        unsigned old = atomicAdd(counter, 1u);  // device-scope by default
        sLast = (old == NBLK - 1);
    }
    __syncthreads();
    if (!sLast) return;

    // ---- last block only: combine 2048 partials, finalize softmax ----
    __threadfence();  // acquire: invalidate caches before reading partials/energies

    const float4* pm4 = (const float4*)pmax;
    const float4* ps4 = (const float4*)psum;
    float4 ma = pm4[tid * 2 + 0], mb = pm4[tid * 2 + 1];
    float4 sa = ps4[tid * 2 + 0], sb = ps4[tid * 2 + 1];
    float M = ma.x, Sv = sa.x;
    MERGE(M, Sv, ma.y, sa.y);
    MERGE(M, Sv, ma.z, sa.z);
    MERGE(M, Sv, ma.w, sa.w);
    MERGE(M, Sv, mb.x, sb.x);
    MERGE(M, Sv, mb.y, sb.y);
    MERGE(M, Sv, mb.z, sb.z);
    MERGE(M, Sv, mb.w, sb.w);

#pragma unroll
    for (int off = 32; off > 0; off >>= 1) {
        float Mo = __shfl_xor(M, off, 64);
        float So = __shfl_xor(Sv, off, 64);
        MERGE(M, Sv, Mo, So);
    }

    __shared__ float fm[4], fs[4];
    if (lane == 0) { fm[wave] = M; fs[wave] = Sv; }
    __syncthreads();
    float Mf = fm[0], Sf = fs[0];
    MERGE(Mf, Sf, fm[1], fs[1]);
    MERGE(Mf, Sf, fm[2], fs[2]);
    MERGE(Mf, Sf, fm[3], fs[3]);
    float inv = 1.0f / Sf;

    // finalize: 8192 float4 over 256 threads = 32 each, coalesced stride-256
    float4* out4 = (float4*)out;
#pragma unroll 8
    for (int k = 0; k < 32; ++k) {
        int idx = k * 256 + tid;
        float4 e = out4[idx];
        float4 o;
        o.x = __expf(e.x - Mf) * inv;
        o.y = __expf(e.y - Mf) * inv;
        o.z = __expf(e.z - Mf) * inv;
        o.w = __expf(e.w - Mf) * inv;
        out4[idx] = o;
    }
}

extern "C" void kernel_launch(void* const* d_in, const int* in_sizes, int n_in,
                              void* d_out, int out_size, void* d_ws, size_t ws_size,
                              hipStream_t stream) {
    const float* hidden = (const float*)d_in[0];  // [H]
    const float* enc    = (const float*)d_in[1];  // [S,H]
    const float* W      = (const float*)d_in[2];  // [H,H]
    // d_in[3] = b: softmax is shift-invariant -> b contributes a constant, skip it.

    float* ws = (float*)d_ws;
    float* v = ws;                                   // 1024
    unsigned* counter = (unsigned*)(ws + 1024);      // 1 (zeroed with v)
    float* pmax = ws + 1088;                         // 2048
    float* psum = ws + 3136;                         // 2048
    float* out = (float*)d_out;                      // energies scratch, then probabilities

    hipMemsetAsync(v, 0, (H + 64) * sizeof(float), stream);  // v + counter
    compute_v<<<dim3(4, 64), 256, 0, stream>>>(W, hidden, v);
    energies_fused<<<NBLK, 256, 0, stream>>>(enc, v, out, pmax, psum, counter);
}

// Round 2
// 202.746 us; speedup vs baseline: 1.5310x; 1.5310x over previous
//
#include <hip/hip_runtime.h>
#include <math.h>

#define H 1024
#define S 32768
#define NBLK (S / 16)  // 2048 energy blocks, 16 rows each

// ws layout (floats):
// [0,1024)      v = W^T @ hidden
// [1088,3136)   per-block max partials   (float4-aligned)
// [3136,5184)   per-block sumexp partials
// energies live in d_out (finalized in-place by combine_finalize)

// K1: v[h] = sum_d W[d*H+h] * hidden[d].
// grid (4, 64): x = column group of 256, y = d-group of 16 rows.
__global__ __launch_bounds__(256) void compute_v(const float* __restrict__ W,
                                                 const float* __restrict__ hidden,
                                                 float* __restrict__ v) {
    int h = blockIdx.x * 256 + threadIdx.x;
    int d0 = blockIdx.y * 16;
    float acc = 0.f;
#pragma unroll
    for (int j = 0; j < 16; ++j) {
        int d = d0 + j;
        acc += W[(size_t)d * H + h] * hidden[d];  // coalesced across lanes
    }
    atomicAdd(&v[h], acc);
}

// online-softmax merge of (M,Sv) with (Mo,So); args must be simple lvalues
#define MERGE(M, Sv, Mo, So)                                         \
    do {                                                             \
        float _mn = fmaxf((M), (Mo));                                \
        (Sv) = (Sv) * __expf((M) - _mn) + (So) * __expf((Mo) - _mn); \
        (M) = _mn;                                                   \
    } while (0)

// K2: energies[s] = enc[s,:] . v ; per-block (max, sumexp) partials.
// 4 waves/block, 4 rows/wave -> 16 rows/block, grid = S/16 = 2048.
// Plain stores only — cross-XCD visibility comes free at the kernel boundary.
__global__ __launch_bounds__(256) void energies_kernel(const float* __restrict__ enc,
                                                       const float* __restrict__ v,
                                                       float* __restrict__ energies,
                                                       float* __restrict__ pmax,
                                                       float* __restrict__ psum) {
    const int lane = threadIdx.x & 63;
    const int wave = threadIdx.x >> 6;

    const float4* v4 = (const float4*)v;
    float4 va = v4[lane];
    float4 vb = v4[64 + lane];
    float4 vc = v4[128 + lane];
    float4 vd = v4[192 + lane];

    const int s0 = blockIdx.x * 16 + wave * 4;
    const float4* base = (const float4*)(enc + (size_t)s0 * H);

    float dot[4];
#pragma unroll
    for (int r = 0; r < 4; ++r) {
        const float4* row = base + r * (H / 4);
        float4 a = row[lane];
        float4 b = row[64 + lane];
        float4 c = row[128 + lane];
        float4 d = row[192 + lane];
        float t = a.x * va.x + a.y * va.y + a.z * va.z + a.w * va.w;
        t += b.x * vb.x + b.y * vb.y + b.z * vb.z + b.w * vb.w;
        t += c.x * vc.x + c.y * vc.y + c.z * vc.z + c.w * vc.w;
        t += d.x * vd.x + d.y * vd.y + d.z * vd.z + d.w * vd.w;
        dot[r] = t;
    }

    // 4 interleaved butterfly reductions (all lanes end with full sums)
#pragma unroll
    for (int off = 32; off > 0; off >>= 1) {
#pragma unroll
        for (int r = 0; r < 4; ++r) dot[r] += __shfl_xor(dot[r], off, 64);
    }

    if (lane == 0) {
        float4 e = make_float4(dot[0], dot[1], dot[2], dot[3]);
        *(float4*)(energies + s0) = e;
    }

    float m = fmaxf(fmaxf(dot[0], dot[1]), fmaxf(dot[2], dot[3]));
    float sum = __expf(dot[0] - m) + __expf(dot[1] - m) +
                __expf(dot[2] - m) + __expf(dot[3] - m);

    __shared__ float wm[4], wsum[4];
    if (lane == 0) { wm[wave] = m; wsum[wave] = sum; }
    __syncthreads();
    if (threadIdx.x == 0) {
        float M = wm[0], Sm = wsum[0];
#pragma unroll
        for (int w = 1; w < 4; ++w) MERGE(M, Sm, wm[w], wsum[w]);
        pmax[blockIdx.x] = M;
        psum[blockIdx.x] = Sm;
    }
}

// K3': fused combine + finalize. Grid = 32 blocks x 256 threads.
// Each block REDUNDANTLY reduces all 2048 partials (16 KB, L2/L3-resident,
// ~2 us latency) -> (M, invSum), then finalizes its own 1024-element slice
// of the output. No cross-block communication -> no fences.
__global__ __launch_bounds__(256) void combine_finalize(const float* __restrict__ pmax,
                                                        const float* __restrict__ psum,
                                                        float* __restrict__ out) {
    const int tid = threadIdx.x;
    const int lane = tid & 63;
    const int wave = tid >> 6;

    // 2048 partials = 512 float4; 256 threads -> 2 float4 of each array
    const float4* pm4 = (const float4*)pmax;
    const float4* ps4 = (const float4*)psum;
    float4 ma = pm4[tid * 2 + 0], mb = pm4[tid * 2 + 1];
    float4 sa = ps4[tid * 2 + 0], sb = ps4[tid * 2 + 1];
    float M = ma.x, Sv = sa.x;
    MERGE(M, Sv, ma.y, sa.y);
    MERGE(M, Sv, ma.z, sa.z);
    MERGE(M, Sv, ma.w, sa.w);
    MERGE(M, Sv, mb.x, sb.x);
    MERGE(M, Sv, mb.y, sb.y);
    MERGE(M, Sv, mb.z, sb.z);
    MERGE(M, Sv, mb.w, sb.w);

#pragma unroll
    for (int off = 32; off > 0; off >>= 1) {
        float Mo = __shfl_xor(M, off, 64);
        float So = __shfl_xor(Sv, off, 64);
        MERGE(M, Sv, Mo, So);
    }

    __shared__ float fm[4], fs[4];
    if (lane == 0) { fm[wave] = M; fs[wave] = Sv; }
    __syncthreads();
    // every thread merges the 4 wave results locally (no second barrier)
    float Mf = fm[0], Sf = fs[0];
    MERGE(Mf, Sf, fm[1], fs[1]);
    MERGE(Mf, Sf, fm[2], fs[2]);
    MERGE(Mf, Sf, fm[3], fs[3]);
    float inv = 1.0f / Sf;

    // finalize this block's slice: 256 float4 per block, 32 blocks = 32768 floats
    int idx = blockIdx.x * 256 + tid;
    float4* out4 = (float4*)out;
    float4 e = out4[idx];
    float4 o;
    o.x = __expf(e.x - Mf) * inv;
    o.y = __expf(e.y - Mf) * inv;
    o.z = __expf(e.z - Mf) * inv;
    o.w = __expf(e.w - Mf) * inv;
    out4[idx] = o;
}

extern "C" void kernel_launch(void* const* d_in, const int* in_sizes, int n_in,
                              void* d_out, int out_size, void* d_ws, size_t ws_size,
                              hipStream_t stream) {
    const float* hidden = (const float*)d_in[0];  // [H]
    const float* enc    = (const float*)d_in[1];  // [S,H]
    const float* W      = (const float*)d_in[2];  // [H,H]
    // d_in[3] = b: softmax is shift-invariant -> b contributes a constant, skip it.

    float* ws = (float*)d_ws;
    float* v = ws;            // 1024
    float* pmax = ws + 1088;  // 2048 (float4-aligned)
    float* psum = ws + 3136;  // 2048
    float* out = (float*)d_out;  // energies scratch, then probabilities

    hipMemsetAsync(v, 0, H * sizeof(float), stream);
    compute_v<<<dim3(4, 64), 256, 0, stream>>>(W, hidden, v);
    energies_kernel<<<NBLK, 256, 0, stream>>>(enc, v, out, pmax, psum);
    combine_finalize<<<S / 4 / 256, 256, 0, stream>>>(pmax, psum, out);
}